// Round 6
// baseline (262.592 us; speedup 1.0000x reference)
//
#include <hip/hip_runtime.h>
#include <hip/hip_bf16.h>

// GQA causal flash attention fwd. fp32 in/out, bf16 MFMA compute, fp32 accum.
// B=2, S=2048, NH=32, KVH=8 (GROUP=4), D=128.
//
// R12 = R10 (verified 104us; R11's KVBLK=32 regressed to 156us and is fully
// reverted) + TWO HEADS PER BLOCK (share kvh => share K/V staging):
//   - Each 64-key staged tile feeds both heads' MFMAs; K/V LDS fragments
//     read ONCE and used twice -> LDS reads and bank conflicts per MFMA
//     halve; KV global traffic halves; barriers per unit work halve.
//   - Grid 512 = exactly 2 blocks/CU, fully co-resident. qt-pairing: CU c
//     hosts qt and 15-qt (bids c and c+256) -> every CU sums to 34 tiles.
//   - VGPR ~240 (acc 128 + qf 64 + cS 32): launch_bounds(256,2) caps 256.
//     2 waves/SIMD with 2x per-wave ILP (HK attn design point).
// Carried from R10: T2 pre-swizzled K/V + global_load_lds (4-way b128
// conflict floor accepted; R11 proved 4-slot V rows degrade to 8-way, so
// KVBLK stays 64); depth-1 dbuf prefetch on standard __syncthreads; T12
// in-register P via cvt_pk_bf16 + permlane32_swap; Q pre-scaled by SCALE2;
// per-subtile softmax->PV. No scheduler-control asm (R7/R9 risk class).

namespace {
constexpr int NH = 32;
constexpr int HD = 128;
constexpr int KVH = 8;
constexpr int SEQ = 2048;
constexpr int NB = 2;
constexpr int QSTRIDE = NH * HD;   // 4096
constexpr int KSTRIDE = KVH * HD;  // 1024
constexpr float SCALE = 0.08838834764831845f;   // 1/sqrt(128)
constexpr float SCALE2 = 0.12751744f;           // SCALE * log2(e)

typedef __attribute__((ext_vector_type(8))) short short8;
typedef __attribute__((ext_vector_type(8))) __bf16 bf16x8;
typedef __attribute__((ext_vector_type(4))) float f32x4;
typedef __attribute__((ext_vector_type(16))) float f32x16;
typedef __attribute__((ext_vector_type(2))) unsigned uint2v;
typedef __attribute__((ext_vector_type(4))) unsigned uint4v;

__device__ inline short cvt_bf16(float f) {
  unsigned u = __builtin_bit_cast(unsigned, f);
  unsigned r = (u + 0x7fffu + ((u >> 16) & 1u)) >> 16;  // RNE
  return (short)r;
}

__device__ inline short8 cvt8(const float* p) {
  f32x4 a = *(const f32x4*)p;
  f32x4 b = *(const f32x4*)(p + 4);
  short8 r;
#pragma unroll
  for (int j = 0; j < 4; ++j) {
    r[j] = cvt_bf16(a[j]);
    r[j + 4] = cvt_bf16(b[j]);
  }
  return r;
}

// scaled variant (Q pre-scale: fold softmax scale into the bf16 convert)
__device__ inline short8 cvt8s(const float* p, float sc) {
  f32x4 a = *(const f32x4*)p;
  f32x4 b = *(const f32x4*)(p + 4);
  short8 r;
#pragma unroll
  for (int j = 0; j < 4; ++j) {
    r[j] = cvt_bf16(a[j] * sc);
    r[j + 4] = cvt_bf16(b[j] * sc);
  }
  return r;
}

__device__ inline bf16x8 asbf(short8 s) { return __builtin_bit_cast(bf16x8, s); }

__device__ inline unsigned cvt_pk_bf16(float lo, float hi) {
  unsigned r;
  asm("v_cvt_pk_bf16_f32 %0, %1, %2" : "=v"(r) : "v"(lo), "v"(hi));
  return r;
}

__device__ inline float fast_exp2(float x) {
#if __has_builtin(__builtin_amdgcn_exp2f)
  return __builtin_amdgcn_exp2f(x);
#else
  return __expf(x * 0.6931471805599453f);
#endif
}

// lo[l] = l<32 ? a[l] : b[l-32];  hi[l] = l<32 ? a[l+32] : b[l]
__device__ inline void swap_halves(unsigned a, unsigned b, unsigned& lo,
                                   unsigned& hi, int half) {
#if __has_builtin(__builtin_amdgcn_permlane32_swap)
  (void)half;
  uint2v r = __builtin_amdgcn_permlane32_swap(a, b, false, false);
  lo = r[0];
  hi = r[1];
#else
  unsigned axf = (unsigned)__shfl_xor((int)a, 32);
  unsigned bxf = (unsigned)__shfl_xor((int)b, 32);
  lo = half ? bxf : a;
  hi = half ? b : axf;
#endif
}
}  // namespace

// ---- fused pre-pass: blocks [0,2048) convert K; [2048,3072) transpose V.
// Both outputs are PRE-SWIZZLED so the main kernel can global_load_lds them
// linearly and read with  byte ^= ((row&7)<<4)  conflict-reduced.
// Kbf row s (256 B): 16B chunk `slot` holds dims (slot ^ (s&7))*8 .. +7.
// Vtb: [bh][tile(=key/64)][d][slot], chunk holds keys 64t+(slot^(d&7))*8..+7.
__global__ __launch_bounds__(256) void convert_kv(const float* __restrict__ K,
                                                  const float* __restrict__ V,
                                                  short* __restrict__ Kbf,
                                                  short* __restrict__ Vtb) {
  __shared__ __align__(16) short t_sh[32 * 136];
  int bid = blockIdx.x;
  int tid = threadIdx.x;
  if (bid < 2048) {
    int flat = bid * 256 + tid;  // 524288 threads, 8 elems each
    int c16 = flat & 15;         // output slot
    int kvh = (flat >> 4) & 7;
    int s = (flat >> 7) & 2047;
    int b = flat >> 18;
    int dsrc = (c16 ^ (s & 7)) << 3;  // XOR-swizzled source dims
    const float* src = K + ((size_t)(b * SEQ + s)) * KSTRIDE + kvh * HD + dsrc;
    short* dst = Kbf + ((size_t)(b * KVH + kvh) * SEQ + s) * HD + (c16 << 3);
    *(short8*)dst = cvt8(src);
    return;
  }
  bid -= 2048;  // 1024 blocks: 32-key strips of V
  int s0 = (bid & 63) * 32;
  int kvh = (bid >> 6) & 7;
  int b = bid >> 9;
  {
    int si = tid >> 3;
    int dseg = (tid & 7) * 16;
    const float* src = V + ((size_t)(b * SEQ + s0 + si)) * KSTRIDE + kvh * HD + dseg;
    short8 a0 = cvt8(src);
    short8 a1 = cvt8(src + 8);
    *(short8*)&t_sh[si * 136 + dseg] = a0;
    *(short8*)&t_sh[si * 136 + dseg + 8] = a1;
  }
  __syncthreads();
  {
    int d = tid >> 1;
    int sseg = (tid & 1) * 16;
    short8 o0, o1;
#pragma unroll
    for (int j = 0; j < 8; ++j) {
      o0[j] = t_sh[(sseg + j) * 136 + d];
      o1[j] = t_sh[(sseg + 8 + j) * 136 + d];
    }
    int m7 = d & 7;
    int cs0 = ((s0 & 63) >> 3) + (sseg >> 3);  // 8-key chunk idx within 64-key tile
    short* dstv = Vtb + (size_t)(b * KVH + kvh) * HD * SEQ +
                  (size_t)(s0 >> 6) * (HD * 64) + d * 64;
    *(short8*)(dstv + ((cs0 ^ m7) << 3)) = o0;
    *(short8*)(dstv + (((cs0 + 1) ^ m7) << 3)) = o1;
  }
}

// ---- main: 128 q-rows/block (32/wave) x TWO heads, 64-key tiles, 32x32x16.
// Grid 512 (= 2 blocks/CU, fully co-resident). qt-pairing: bids c and c+256
// land on the same CU (round-robin heuristic) and carry qt and 15-qt.
__global__ __launch_bounds__(256, 2) void gqa_attn(
    const float* __restrict__ Q, const short* __restrict__ Kbf,
    const short* __restrict__ Vtb, float* __restrict__ O) {
  __shared__ __align__(16) short k_sh[2][64 * 128];   // 2 x 16 KiB, swizzled rows
  __shared__ __align__(16) short v_sh[2][128 * 64];   // 2 x 16 KiB, swizzled rows

  const int tid = threadIdx.x;
  const int wid = tid >> 6;
  const int lane = tid & 63;
  const int l31 = lane & 31;
  const int half = lane >> 5;
  const int vx = (((l31 & 7) ^ half) << 4);  // per-lane swizzle term

  const int bid = blockIdx.x;
  const int g = bid >> 5;                       // 0..15
  const int qt = (bid < 256) ? (15 - g) : (g - 8);  // CU pair sums to 15
  const int idx = bid & 31;
  const int hp = idx & 15;                      // head pair 0..15
  const int b = idx >> 4;
  const int h0 = hp * 2;                        // heads h0, h0+1 share kvh
  const int kvh = hp >> 1;
  const int q0 = qt << 7;

  const int row_min = q0 + wid * 32;
  const int row_top = row_min + 31;
  const int qrow = row_min + l31;

  // Q fragments for BOTH heads = B operand of swapped QK^T.
  // Pre-scaled by SCALE2: QK^T MFMA directly yields exp2-ready scores.
  const float* qp = Q + (size_t)(b * SEQ + qrow) * QSTRIDE + h0 * HD + half * 8;
  short8 qa[8], qb[8];
#pragma unroll
  for (int st = 0; st < 8; ++st) qa[st] = cvt8s(qp + st * 16, SCALE2);
#pragma unroll
  for (int st = 0; st < 8; ++st) qb[st] = cvt8s(qp + HD + st * 16, SCALE2);

  f32x16 acc0[4], acc1[4];
#pragma unroll
  for (int t = 0; t < 4; ++t)
#pragma unroll
    for (int i = 0; i < 16; ++i) { acc0[t][i] = 0.f; acc1[t][i] = 0.f; }
  float la0 = 0.f, la1 = 0.f;

  const char* kbase = (const char*)(Kbf + (size_t)(b * KVH + kvh) * SEQ * HD);
  const char* vbase = (const char*)(Vtb + (size_t)(b * KVH + kvh) * HD * SEQ);
  const int sgo = wid * 4096 + lane * 16;  // this wave's deposit slice

  // 8 x global_load_lds(16B) per wave per tile: 4 K-chunks + 4 V-chunks.
  // LDS dest is linear (wave-uniform base + lane*16); source is pre-swizzled.
  auto stage = [&](int bsel, int kb_) {
    const char* kg = kbase + (size_t)kb_ * 256 + sgo;
    const char* vg = vbase + (size_t)(kb_ >> 6) * 16384 + sgo;
    char* kl = (char*)&k_sh[bsel][0] + wid * 4096;
    char* vl = (char*)&v_sh[bsel][0] + wid * 4096;
#pragma unroll
    for (int i = 0; i < 4; ++i) {
      __builtin_amdgcn_global_load_lds((const void*)(kg + i * 1024),
                                       (void*)(kl + i * 1024), 16, 0, 0);
      __builtin_amdgcn_global_load_lds((const void*)(vg + i * 1024),
                                       (void*)(vl + i * 1024), 16, 0, 0);
    }
  };

  const int nT = 2 * qt + 2;
  stage(0, 0);

#pragma unroll 1
  for (int it = 0; it < nT; ++it) {
    const int kb = it << 6;
    const int cur = it & 1;
    // Drain: this wave's outstanding stage loads (issued one full compute
    // phase ago, except iteration 0) + all waves' reads of buffer cur^1
    // finished. Standard __syncthreads semantics — no hand-rolled waits.
    __syncthreads();
    // Prefetch next tile into the buffer everyone just finished reading.
    if (it + 1 < nT) stage(cur ^ 1, kb + 64);

    if (kb <= row_top) {
      const char* kB = (const char*)&k_sh[cur][0] + l31 * 256;
      const char* vB = (const char*)&v_sh[cur][0] + l31 * 128;

      const bool diag = (kb + 63 > row_min);
      const int rel = qrow - kb - 4 * half;

      // ---- per 32-key subtile: QK (shared K reads), softmax x2, PV
      // (shared V reads). K/V fragments read ONCE, used by both heads.
#pragma unroll
      for (int s = 0; s < 2; ++s) {
        f32x16 c0, c1;
#pragma unroll
        for (int i = 0; i < 16; ++i) { c0[i] = 0.f; c1[i] = 0.f; }
#pragma unroll
        for (int st = 0; st < 8; ++st) {
          const int so = vx ^ (st << 5);  // ((2st+half)^(row&7))<<4
          short8 k0 = *(const short8*)(kB + s * 8192 + so);
          bf16x8 kb16 = asbf(k0);
          c0 = __builtin_amdgcn_mfma_f32_32x32x16_bf16(kb16, asbf(qa[st]), c0, 0, 0, 0);
          c1 = __builtin_amdgcn_mfma_f32_32x32x16_bf16(kb16, asbf(qb[st]), c1, 0, 0, 0);
        }

        // fixed-base softmax, in-register (scores pre-scaled for exp2)
        if (diag) {
#pragma unroll
          for (int r = 0; r < 16; ++r) {
            const int kc_ = (r & 3) + 8 * (r >> 2) + s * 32;
            const bool msk = kc_ > rel;
            float s0v = msk ? -1e30f : c0[r];
            float s1v = msk ? -1e30f : c1[r];
            float e0 = fast_exp2(s0v);
            float e1 = fast_exp2(s1v);
            c0[r] = e0; la0 += e0;
            c1[r] = e1; la1 += e1;
          }
        } else {
#pragma unroll
          for (int r = 0; r < 16; ++r) {
            float e0 = fast_exp2(c0[r]);
            float e1 = fast_exp2(c1[r]);
            c0[r] = e0; la0 += e0;
            c1[r] = e1; la1 += e1;
          }
        }

        // P -> bf16 A-frags in-register (T12), both heads
        bf16x8 pa0[2], pa1[2];
        {
          unsigned Ag[4], Bg[4];
#pragma unroll
          for (int g2 = 0; g2 < 4; ++g2) {
            Ag[g2] = cvt_pk_bf16(c0[4 * g2], c0[4 * g2 + 1]);
            Bg[g2] = cvt_pk_bf16(c0[4 * g2 + 2], c0[4 * g2 + 3]);
          }
#pragma unroll
          for (int kc = 0; kc < 2; ++kc) {
            unsigned a_lo, a_hi, b_lo, b_hi;
            swap_halves(Ag[2 * kc], Ag[2 * kc + 1], a_lo, a_hi, half);
            swap_halves(Bg[2 * kc], Bg[2 * kc + 1], b_lo, b_hi, half);
            uint4v wv;
            wv[0] = a_lo; wv[1] = b_lo; wv[2] = a_hi; wv[3] = b_hi;
            pa0[kc] = __builtin_bit_cast(bf16x8, wv);
          }
#pragma unroll
          for (int g2 = 0; g2 < 4; ++g2) {
            Ag[g2] = cvt_pk_bf16(c1[4 * g2], c1[4 * g2 + 1]);
            Bg[g2] = cvt_pk_bf16(c1[4 * g2 + 2], c1[4 * g2 + 3]);
          }
#pragma unroll
          for (int kc = 0; kc < 2; ++kc) {
            unsigned a_lo, a_hi, b_lo, b_hi;
            swap_halves(Ag[2 * kc], Ag[2 * kc + 1], a_lo, a_hi, half);
            swap_halves(Bg[2 * kc], Bg[2 * kc + 1], b_lo, b_hi, half);
            uint4v wv;
            wv[0] = a_lo; wv[1] = b_lo; wv[2] = a_hi; wv[3] = b_hi;
            pa1[kc] = __builtin_bit_cast(bf16x8, wv);
          }
        }

        // PV: V fragment read once, used by both heads
#pragma unroll
        for (int kc = 0; kc < 2; ++kc) {
          const int vo = vx ^ ((s << 6) | (kc << 5));
#pragma unroll
          for (int t = 0; t < 4; ++t) {
            short8 vv = *(const short8*)(vB + t * 4096 + vo);
            bf16x8 vb16 = asbf(vv);
            acc0[t] = __builtin_amdgcn_mfma_f32_32x32x16_bf16(pa0[kc], vb16, acc0[t], 0, 0, 0);
            acc1[t] = __builtin_amdgcn_mfma_f32_32x32x16_bf16(pa1[kc], vb16, acc1[t], 0, 0, 0);
          }
        }
      }
    }
  }

  // ---- epilogue: row-sum = self + partner half; redistribute inv via shfl
  float ls0 = la0 + __shfl_xor(la0, 32);
  float ls1 = la1 + __shfl_xor(la1, 32);
  float iv0 = 1.f / ls0;
  float iv1 = 1.f / ls1;
  float* ob = O + (size_t)(b * SEQ + row_min) * QSTRIDE + h0 * HD;
#pragma unroll
  for (int i = 0; i < 16; ++i) {
    const int row = (i & 3) + 8 * (i >> 2) + 4 * half;
    const float v0 = __shfl(iv0, row & 31);
    const float v1 = __shfl(iv1, row & 31);
#pragma unroll
    for (int t = 0; t < 4; ++t) {
      ob[(size_t)row * QSTRIDE + t * 32 + l31] = acc0[t][i] * v0;
      ob[(size_t)row * QSTRIDE + HD + t * 32 + l31] = acc1[t][i] * v1;
    }
  }
}

// ---------------- fallback (verified R2 kernel) if ws too small
namespace {
constexpr int FKL = 136, FVL = 40, FPL = 40;
constexpr float NEGF = -50000.0f;
}
__global__ __launch_bounds__(256) void gqa_attn_f32(
    const float* __restrict__ Q, const float* __restrict__ K,
    const float* __restrict__ V, float* __restrict__ O) {
  __shared__ __align__(16) short k_sh[32 * FKL];
  __shared__ __align__(16) short v_sh[HD * FVL];
  __shared__ __align__(16) short p_sh[4 * 16 * FPL];
  const int tid = threadIdx.x, wid = tid >> 6, lane = tid & 63;
  const int col = lane & 15, quad = lane >> 4;
  const int bid = blockIdx.x;
  const int qt = bid & 31, h = (bid >> 5) & 31, b = bid >> 10;
  const int kvh = h >> 2, q0 = qt << 6;
  const int qrow = q0 + wid * 16 + col;
  const float* qptr = Q + (size_t)(b * SEQ + qrow) * QSTRIDE + h * HD + quad * 8;
  short8 qf[4];
#pragma unroll
  for (int c = 0; c < 4; ++c) qf[c] = cvt8(qptr + c * 32);
  f32x4 acc[8];
#pragma unroll
  for (int t = 0; t < 8; ++t) acc[t] = (f32x4){0.f, 0.f, 0.f, 0.f};
  float m_run[4] = {-1e30f, -1e30f, -1e30f, -1e30f};
  float l_run[4] = {0.f, 0.f, 0.f, 0.f};
  const float* kbase = K + (size_t)b * SEQ * KSTRIDE + kvh * HD;
  const float* vbase = V + (size_t)b * SEQ * KSTRIDE + kvh * HD;
  const int skey = tid & 31, sd = (tid >> 5) << 4;
  const int q_reg_row = q0 + wid * 16 + quad * 4;
  const int nT = (q0 >> 5) + 2;
  for (int it = 0; it < nT; ++it) {
    const int kb = it << 5;
    __syncthreads();
    {
      const float* ks = kbase + (size_t)(kb + skey) * KSTRIDE + sd;
      short8 k0 = cvt8(ks), k1 = cvt8(ks + 8);
      *(short8*)&k_sh[skey * FKL + sd] = k0;
      *(short8*)&k_sh[skey * FKL + sd + 8] = k1;
      const float* vs = vbase + (size_t)(kb + skey) * KSTRIDE + sd;
      short8 v0 = cvt8(vs), v1 = cvt8(vs + 8);
#pragma unroll
      for (int j = 0; j < 8; ++j) v_sh[(sd + j) * FVL + skey] = v0[j];
#pragma unroll
      for (int j = 0; j < 8; ++j) v_sh[(sd + 8 + j) * FVL + skey] = v1[j];
    }
    __syncthreads();
    f32x4 cL = {0.f, 0.f, 0.f, 0.f}, cR = {0.f, 0.f, 0.f, 0.f};
#pragma unroll
    for (int c = 0; c < 4; ++c) {
      short8 bL = *(const short8*)&k_sh[col * FKL + c * 32 + quad * 8];
      short8 bR = *(const short8*)&k_sh[(col + 16) * FKL + c * 32 + quad * 8];
      cL = __builtin_amdgcn_mfma_f32_16x16x32_bf16(asbf(qf[c]), asbf(bL), cL, 0, 0, 0);
      cR = __builtin_amdgcn_mfma_f32_16x16x32_bf16(asbf(qf[c]), asbf(bR), cR, 0, 0, 0);
    }
    float pL[4], pR[4], alpha[4];
#pragma unroll
    for (int r = 0; r < 4; ++r) {
      const int qr = q_reg_row + r;
      float sL = (kb + col <= qr) ? cL[r] * SCALE : NEGF;
      float sR = (kb + 16 + col <= qr) ? cR[r] * SCALE : NEGF;
      float mx = fmaxf(sL, sR);
      mx = fmaxf(mx, __shfl_xor(mx, 1));
      mx = fmaxf(mx, __shfl_xor(mx, 2));
      mx = fmaxf(mx, __shfl_xor(mx, 4));
      mx = fmaxf(mx, __shfl_xor(mx, 8));
      float nm = fmaxf(m_run[r], mx);
      alpha[r] = __expf(m_run[r] - nm);
      m_run[r] = nm;
      pL[r] = __expf(sL - nm);
      pR[r] = __expf(sR - nm);
      float ps = pL[r] + pR[r];
      ps += __shfl_xor(ps, 1);
      ps += __shfl_xor(ps, 2);
      ps += __shfl_xor(ps, 4);
      ps += __shfl_xor(ps, 8);
      l_run[r] = l_run[r] * alpha[r] + ps;
    }
#pragma unroll
    for (int t = 0; t < 8; ++t)
#pragma unroll
      for (int r = 0; r < 4; ++r) acc[t][r] *= alpha[r];
    short* pw = &p_sh[wid * 16 * FPL];
#pragma unroll
    for (int r = 0; r < 4; ++r) {
      pw[(quad * 4 + r) * FPL + col] = cvt_bf16(pL[r]);
      pw[(quad * 4 + r) * FPL + col + 16] = cvt_bf16(pR[r]);
    }
    __syncthreads();
    short8 pa = *(const short8*)&pw[col * FPL + quad * 8];
#pragma unroll
    for (int t = 0; t < 8; ++t) {
      short8 vb = *(const short8*)&v_sh[(t * 16 + col) * FVL + quad * 8];
      acc[t] = __builtin_amdgcn_mfma_f32_16x16x32_bf16(asbf(pa), asbf(vb), acc[t], 0, 0, 0);
    }
  }
  float inv[4];
#pragma unroll
  for (int r = 0; r < 4; ++r) inv[r] = 1.f / l_run[r];
  float* ob = O + (size_t)(b * SEQ + q_reg_row) * QSTRIDE + h * HD;
#pragma unroll
  for (int r = 0; r < 4; ++r)
#pragma unroll
    for (int t = 0; t < 8; ++t)
      ob[(size_t)r * QSTRIDE + t * 16 + col] = acc[t][r] * inv[r];
}

extern "C" void kernel_launch(void* const* d_in, const int* in_sizes, int n_in,
                              void* d_out, int out_size, void* d_ws, size_t ws_size,
                              hipStream_t stream) {
  const float* Q = (const float*)d_in[0];
  const float* K = (const float*)d_in[1];
  const float* V = (const float*)d_in[2];
  float* O = (float*)d_out;
  const size_t kv_elems = (size_t)NB * KVH * SEQ * HD;  // 4,194,304
  const size_t need = kv_elems * 2 * sizeof(short);     // 16 MiB
  if (ws_size >= need) {
    short* Kbf = (short*)d_ws;
    short* Vtb = Kbf + kv_elems;
    convert_kv<<<3072, 256, 0, stream>>>(K, V, Kbf, Vtb);
    gqa_attn<<<512, 256, 0, stream>>>(Q, Kbf, Vtb, O);
  } else {
    gqa_attn_f32<<<2048, 256, 0, stream>>>(Q, K, V, O);
  }
}

// Round 9
// 209.685 us; speedup vs baseline: 1.2523x; 1.2523x over previous
//
#include <hip/hip_runtime.h>
#include <hip/hip_bf16.h>

// GQA causal flash attention fwd. fp32 in/out, bf16 MFMA compute, fp32 accum.
// B=2, S=2048, NH=32, KVH=8 (GROUP=4), D=128.
//
// R15 = R10 (verified 104us; the R13/R14 8-wave variant failed twice with
// bit-identical error -> deterministic unfound bug, structure abandoned)
// + two pure-dataflow changes:
//  (1) l via MFMA: lacc = mfma(pa, ONES, lacc). Deletes 32 VALU adds/tile
//      AND the epilogue shfl reduce entirely -- mfma(P,1)'s D-layout gives
//      each lane its row-sums at the SAME i->row mapping as acc, so
//      inv_i[i] = 1/lacc[i] directly. Normalizer now sums bf16-rounded P,
//      consistent with the PV numerator. +4 MFMA/tile on a 28%-busy pipe.
//  (2) per-s fusion: QK st-loop moved inside the s-loop (cS is a single
//      f32x16, -16 VGPR). Each 32-key subtile is read->MFMA->softmax->cvt->
//      MFMA -- short mixed-pipe phases so co-resident waves interleave
//      pipes instead of convoying (LDS ~50-56% of wall; VALU 25%).
// Carried from R10: T2 pre-swizzled K/V + global_load_lds staging (4-way
// b128 conflict floor accepted); depth-1 dbuf prefetch on standard
// __syncthreads; T12 in-register P via cvt_pk_bf16 + permlane32_swap;
// Q pre-scaled by SCALE2. No scheduler-control asm (R7/R9 risk class).

namespace {
constexpr int NH = 32;
constexpr int HD = 128;
constexpr int KVH = 8;
constexpr int SEQ = 2048;
constexpr int NB = 2;
constexpr int QSTRIDE = NH * HD;   // 4096
constexpr int KSTRIDE = KVH * HD;  // 1024
constexpr float SCALE = 0.08838834764831845f;   // 1/sqrt(128)
constexpr float SCALE2 = 0.12751744f;           // SCALE * log2(e)

typedef __attribute__((ext_vector_type(8))) short short8;
typedef __attribute__((ext_vector_type(8))) __bf16 bf16x8;
typedef __attribute__((ext_vector_type(4))) float f32x4;
typedef __attribute__((ext_vector_type(16))) float f32x16;
typedef __attribute__((ext_vector_type(2))) unsigned uint2v;
typedef __attribute__((ext_vector_type(4))) unsigned uint4v;

__device__ inline short cvt_bf16(float f) {
  unsigned u = __builtin_bit_cast(unsigned, f);
  unsigned r = (u + 0x7fffu + ((u >> 16) & 1u)) >> 16;  // RNE
  return (short)r;
}

__device__ inline short8 cvt8(const float* p) {
  f32x4 a = *(const f32x4*)p;
  f32x4 b = *(const f32x4*)(p + 4);
  short8 r;
#pragma unroll
  for (int j = 0; j < 4; ++j) {
    r[j] = cvt_bf16(a[j]);
    r[j + 4] = cvt_bf16(b[j]);
  }
  return r;
}

// scaled variant (Q pre-scale: fold softmax scale into the bf16 convert)
__device__ inline short8 cvt8s(const float* p, float sc) {
  f32x4 a = *(const f32x4*)p;
  f32x4 b = *(const f32x4*)(p + 4);
  short8 r;
#pragma unroll
  for (int j = 0; j < 4; ++j) {
    r[j] = cvt_bf16(a[j] * sc);
    r[j + 4] = cvt_bf16(b[j] * sc);
  }
  return r;
}

__device__ inline bf16x8 asbf(short8 s) { return __builtin_bit_cast(bf16x8, s); }

__device__ inline unsigned cvt_pk_bf16(float lo, float hi) {
  unsigned r;
  asm("v_cvt_pk_bf16_f32 %0, %1, %2" : "=v"(r) : "v"(lo), "v"(hi));
  return r;
}

__device__ inline float fast_exp2(float x) {
#if __has_builtin(__builtin_amdgcn_exp2f)
  return __builtin_amdgcn_exp2f(x);
#else
  return __expf(x * 0.6931471805599453f);
#endif
}

// lo[l] = l<32 ? a[l] : b[l-32];  hi[l] = l<32 ? a[l+32] : b[l]
__device__ inline void swap_halves(unsigned a, unsigned b, unsigned& lo,
                                   unsigned& hi, int half) {
#if __has_builtin(__builtin_amdgcn_permlane32_swap)
  (void)half;
  uint2v r = __builtin_amdgcn_permlane32_swap(a, b, false, false);
  lo = r[0];
  hi = r[1];
#else
  unsigned axf = (unsigned)__shfl_xor((int)a, 32);
  unsigned bxf = (unsigned)__shfl_xor((int)b, 32);
  lo = half ? bxf : a;
  hi = half ? b : axf;
#endif
}
}  // namespace

// ---- fused pre-pass: blocks [0,2048) convert K; [2048,3072) transpose V.
// Both outputs are PRE-SWIZZLED so the main kernel can global_load_lds them
// linearly and read with  byte ^= ((row&7)<<4)  conflict-reduced.
// Kbf row s (256 B): 16B chunk `slot` holds dims (slot ^ (s&7))*8 .. +7.
// Vtb: [bh][tile(=key/64)][d][slot], chunk holds keys 64t+(slot^(d&7))*8..+7.
__global__ __launch_bounds__(256) void convert_kv(const float* __restrict__ K,
                                                  const float* __restrict__ V,
                                                  short* __restrict__ Kbf,
                                                  short* __restrict__ Vtb) {
  __shared__ __align__(16) short t_sh[32 * 136];
  int bid = blockIdx.x;
  int tid = threadIdx.x;
  if (bid < 2048) {
    int flat = bid * 256 + tid;  // 524288 threads, 8 elems each
    int c16 = flat & 15;         // output slot
    int kvh = (flat >> 4) & 7;
    int s = (flat >> 7) & 2047;
    int b = flat >> 18;
    int dsrc = (c16 ^ (s & 7)) << 3;  // XOR-swizzled source dims
    const float* src = K + ((size_t)(b * SEQ + s)) * KSTRIDE + kvh * HD + dsrc;
    short* dst = Kbf + ((size_t)(b * KVH + kvh) * SEQ + s) * HD + (c16 << 3);
    *(short8*)dst = cvt8(src);
    return;
  }
  bid -= 2048;  // 1024 blocks: 32-key strips of V
  int s0 = (bid & 63) * 32;
  int kvh = (bid >> 6) & 7;
  int b = bid >> 9;
  {
    int si = tid >> 3;
    int dseg = (tid & 7) * 16;
    const float* src = V + ((size_t)(b * SEQ + s0 + si)) * KSTRIDE + kvh * HD + dseg;
    short8 a0 = cvt8(src);
    short8 a1 = cvt8(src + 8);
    *(short8*)&t_sh[si * 136 + dseg] = a0;
    *(short8*)&t_sh[si * 136 + dseg + 8] = a1;
  }
  __syncthreads();
  {
    int d = tid >> 1;
    int sseg = (tid & 1) * 16;
    short8 o0, o1;
#pragma unroll
    for (int j = 0; j < 8; ++j) {
      o0[j] = t_sh[(sseg + j) * 136 + d];
      o1[j] = t_sh[(sseg + 8 + j) * 136 + d];
    }
    int m7 = d & 7;
    int cs0 = ((s0 & 63) >> 3) + (sseg >> 3);  // 8-key chunk idx within 64-key tile
    short* dstv = Vtb + (size_t)(b * KVH + kvh) * HD * SEQ +
                  (size_t)(s0 >> 6) * (HD * 64) + d * 64;
    *(short8*)(dstv + ((cs0 ^ m7) << 3)) = o0;
    *(short8*)(dstv + (((cs0 + 1) ^ m7) << 3)) = o1;
  }
}

// ---- main: 128 q-rows/block (32/wave), 64-key tiles, 32x32x16 MFMA.
// Grid 1024, globally qt-descending (LPT): bid>>6 -> qt index.
__global__ __launch_bounds__(256, 2) void gqa_attn(
    const float* __restrict__ Q, const short* __restrict__ Kbf,
    const short* __restrict__ Vtb, float* __restrict__ O) {
  __shared__ __align__(16) short k_sh[2][64 * 128];   // 2 x 16 KiB, swizzled rows
  __shared__ __align__(16) short v_sh[2][128 * 64];   // 2 x 16 KiB, swizzled rows

  const int tid = threadIdx.x;
  const int wid = tid >> 6;
  const int lane = tid & 63;
  const int l31 = lane & 31;
  const int half = lane >> 5;
  const int vx = (((l31 & 7) ^ half) << 4);  // per-lane swizzle term

  const int bid = blockIdx.x;
  const int qt = 15 - (bid >> 6);   // LPT: all 32-tile jobs dispatch first
  const int h = bid & 31;
  const int b = (bid >> 5) & 1;
  const int kvh = h >> 2;
  const int q0 = qt << 7;

  const int row_min = q0 + wid * 32;
  const int row_top = row_min + 31;
  const int qrow = row_min + l31;

  // Q fragments = B operand of swapped QK^T: n=qrow, k = st*16 + half*8 + j
  // Pre-scaled by SCALE2: QK^T MFMA directly yields exp2-ready scores.
  const float* qptr = Q + (size_t)(b * SEQ + qrow) * QSTRIDE + h * HD + half * 8;
  short8 qf[8];
#pragma unroll
  for (int st = 0; st < 8; ++st) qf[st] = cvt8s(qptr + st * 16, SCALE2);

  // ONES B-frag for the l-row-sum MFMA (bf16 1.0 = 0x3F80)
  short8 ones_s;
#pragma unroll
  for (int j = 0; j < 8; ++j) ones_s[j] = (short)0x3F80;
  const bf16x8 ONES = asbf(ones_s);

  f32x16 acc[4];
#pragma unroll
  for (int t = 0; t < 4; ++t)
#pragma unroll
    for (int i = 0; i < 16; ++i) acc[t][i] = 0.f;
  f32x16 lacc;
#pragma unroll
  for (int i = 0; i < 16; ++i) lacc[i] = 0.f;

  const char* kbase = (const char*)(Kbf + (size_t)(b * KVH + kvh) * SEQ * HD);
  const char* vbase = (const char*)(Vtb + (size_t)(b * KVH + kvh) * HD * SEQ);
  const int sgo = wid * 4096 + lane * 16;  // this wave's deposit slice

  // 8 x global_load_lds(16B) per wave per tile: 4 K-chunks + 4 V-chunks.
  // LDS dest is linear (wave-uniform base + lane*16); source is pre-swizzled.
  auto stage = [&](int bsel, int kb_) {
    const char* kg = kbase + (size_t)kb_ * 256 + sgo;
    const char* vg = vbase + (size_t)(kb_ >> 6) * 16384 + sgo;
    char* kl = (char*)&k_sh[bsel][0] + wid * 4096;
    char* vl = (char*)&v_sh[bsel][0] + wid * 4096;
#pragma unroll
    for (int i = 0; i < 4; ++i) {
      __builtin_amdgcn_global_load_lds((const void*)(kg + i * 1024),
                                       (void*)(kl + i * 1024), 16, 0, 0);
      __builtin_amdgcn_global_load_lds((const void*)(vg + i * 1024),
                                       (void*)(vl + i * 1024), 16, 0, 0);
    }
  };

  const int nT = 2 * qt + 2;
  stage(0, 0);

#pragma unroll 1
  for (int it = 0; it < nT; ++it) {
    const int kb = it << 6;
    const int cur = it & 1;
    // Drain: this wave's outstanding stage loads (issued one full compute
    // phase ago, except iteration 0) + all waves' reads of buffer cur^1
    // finished. Standard __syncthreads semantics — no hand-rolled waits.
    __syncthreads();
    // Prefetch next tile into the buffer everyone just finished reading.
    if (it + 1 < nT) stage(cur ^ 1, kb + 64);

    if (kb <= row_top) {
      const char* kB = (const char*)&k_sh[cur][0] + l31 * 256;
      const char* vB = (const char*)&v_sh[cur][0] + l31 * 128;
      const bool diag = (kb + 63 > row_min);
      const int rel = qrow - kb - 4 * half;

      // ---- fully fused per 32-key subtile: QK -> softmax -> cvt -> l/PV.
#pragma unroll
      for (int s = 0; s < 2; ++s) {
        // S^T = K Q^T for this subtile: lane holds q-row `qrow` at keys
        // (r&3)+8*(r>>2)+4*half (+32s)
        f32x16 cS;
#pragma unroll
        for (int i = 0; i < 16; ++i) cS[i] = 0.f;
#pragma unroll
        for (int st = 0; st < 8; ++st) {
          const int so = vx ^ (st << 5);  // ((2st+half)^(row&7))<<4
          short8 k0 = *(const short8*)(kB + s * 8192 + so);
          cS = __builtin_amdgcn_mfma_f32_32x32x16_bf16(asbf(k0), asbf(qf[st]), cS, 0, 0, 0);
        }

        // fixed-base softmax, in-register (scores pre-scaled for exp2)
        if (diag) {
#pragma unroll
          for (int r = 0; r < 16; ++r) {
            const int kc_ = (r & 3) + 8 * (r >> 2);
            float sc = cS[r];
            if (kc_ + s * 32 > rel) sc = -1e30f;
            cS[r] = fast_exp2(sc);
          }
        } else {
#pragma unroll
          for (int r = 0; r < 16; ++r) cS[r] = fast_exp2(cS[r]);
        }

        // P -> bf16 A-frags in-register (T12)
        unsigned Ag[4], Bg[4];
#pragma unroll
        for (int g2 = 0; g2 < 4; ++g2) {
          Ag[g2] = cvt_pk_bf16(cS[4 * g2], cS[4 * g2 + 1]);
          Bg[g2] = cvt_pk_bf16(cS[4 * g2 + 2], cS[4 * g2 + 3]);
        }
#pragma unroll
        for (int kc = 0; kc < 2; ++kc) {
          unsigned a_lo, a_hi, b_lo, b_hi;
          swap_halves(Ag[2 * kc], Ag[2 * kc + 1], a_lo, a_hi, half);
          swap_halves(Bg[2 * kc], Bg[2 * kc + 1], b_lo, b_hi, half);
          uint4v wv;
          wv[0] = a_lo;  // keys base+0,1
          wv[1] = b_lo;  // keys base+2,3
          wv[2] = a_hi;  // keys base+4,5
          wv[3] = b_hi;  // keys base+6,7
          bf16x8 pa = __builtin_bit_cast(bf16x8, wv);
          // l row-sums ride the MFMA pipe: D rows have the SAME i->row
          // mapping as acc, so the epilogue uses lacc[i] directly.
          lacc = __builtin_amdgcn_mfma_f32_32x32x16_bf16(pa, ONES, lacc, 0, 0, 0);
          const int vo = vx ^ ((s << 6) | (kc << 5));
#pragma unroll
          for (int t = 0; t < 4; ++t) {
            short8 vv = *(const short8*)(vB + t * 4096 + vo);
            acc[t] = __builtin_amdgcn_mfma_f32_32x32x16_bf16(pa, asbf(vv), acc[t], 0, 0, 0);
          }
        }
      }
    }
  }

  // ---- epilogue: normalize with lacc (same i->row mapping as acc), store.
  float inv_i[16];
#pragma unroll
  for (int i = 0; i < 16; ++i) inv_i[i] = 1.f / lacc[i];
  float* ob = O + (size_t)(b * SEQ + row_min) * QSTRIDE + h * HD;
#pragma unroll
  for (int t = 0; t < 4; ++t)
#pragma unroll
    for (int i = 0; i < 16; ++i) {
      const int row = (i & 3) + 8 * (i >> 2) + 4 * half;
      ob[(size_t)row * QSTRIDE + t * 32 + l31] = acc[t][i] * inv_i[i];
    }
}

// ---------------- fallback (verified R2 kernel) if ws too small
namespace {
constexpr int FKL = 136, FVL = 40, FPL = 40;
constexpr float NEGF = -50000.0f;
}
__global__ __launch_bounds__(256) void gqa_attn_f32(
    const float* __restrict__ Q, const float* __restrict__ K,
    const float* __restrict__ V, float* __restrict__ O) {
  __shared__ __align__(16) short k_sh[32 * FKL];
  __shared__ __align__(16) short v_sh[HD * FVL];
  __shared__ __align__(16) short p_sh[4 * 16 * FPL];
  const int tid = threadIdx.x, wid = tid >> 6, lane = tid & 63;
  const int col = lane & 15, quad = lane >> 4;
  const int bid = blockIdx.x;
  const int qt = bid & 31, h = (bid >> 5) & 31, b = bid >> 10;
  const int kvh = h >> 2, q0 = qt << 6;
  const int qrow = q0 + wid * 16 + col;
  const float* qptr = Q + (size_t)(b * SEQ + qrow) * QSTRIDE + h * HD + quad * 8;
  short8 qf[4];
#pragma unroll
  for (int c = 0; c < 4; ++c) qf[c] = cvt8(qptr + c * 32);
  f32x4 acc[8];
#pragma unroll
  for (int t = 0; t < 8; ++t) acc[t] = (f32x4){0.f, 0.f, 0.f, 0.f};
  float m_run[4] = {-1e30f, -1e30f, -1e30f, -1e30f};
  float l_run[4] = {0.f, 0.f, 0.f, 0.f};
  const float* kbase = K + (size_t)b * SEQ * KSTRIDE + kvh * HD;
  const float* vbase = V + (size_t)b * SEQ * KSTRIDE + kvh * HD;
  const int skey = tid & 31, sd = (tid >> 5) << 4;
  const int q_reg_row = q0 + wid * 16 + quad * 4;
  const int nT = (q0 >> 5) + 2;
  for (int it = 0; it < nT; ++it) {
    const int kb = it << 5;
    __syncthreads();
    {
      const float* ks = kbase + (size_t)(kb + skey) * KSTRIDE + sd;
      short8 k0 = cvt8(ks), k1 = cvt8(ks + 8);
      *(short8*)&k_sh[skey * FKL + sd] = k0;
      *(short8*)&k_sh[skey * FKL + sd + 8] = k1;
      const float* vs = vbase + (size_t)(kb + skey) * KSTRIDE + sd;
      short8 v0 = cvt8(vs), v1 = cvt8(vs + 8);
#pragma unroll
      for (int j = 0; j < 8; ++j) v_sh[(sd + j) * FVL + skey] = v0[j];
#pragma unroll
      for (int j = 0; j < 8; ++j) v_sh[(sd + 8 + j) * FVL + skey] = v1[j];
    }
    __syncthreads();
    f32x4 cL = {0.f, 0.f, 0.f, 0.f}, cR = {0.f, 0.f, 0.f, 0.f};
#pragma unroll
    for (int c = 0; c < 4; ++c) {
      short8 bL = *(const short8*)&k_sh[col * FKL + c * 32 + quad * 8];
      short8 bR = *(const short8*)&k_sh[(col + 16) * FKL + c * 32 + quad * 8];
      cL = __builtin_amdgcn_mfma_f32_16x16x32_bf16(asbf(qf[c]), asbf(bL), cL, 0, 0, 0);
      cR = __builtin_amdgcn_mfma_f32_16x16x32_bf16(asbf(qf[c]), asbf(bR), cR, 0, 0, 0);
    }
    float pL[4], pR[4], alpha[4];
#pragma unroll
    for (int r = 0; r < 4; ++r) {
      const int qr = q_reg_row + r;
      float sL = (kb + col <= qr) ? cL[r] * SCALE : NEGF;
      float sR = (kb + 16 + col <= qr) ? cR[r] * SCALE : NEGF;
      float mx = fmaxf(sL, sR);
      mx = fmaxf(mx, __shfl_xor(mx, 1));
      mx = fmaxf(mx, __shfl_xor(mx, 2));
      mx = fmaxf(mx, __shfl_xor(mx, 4));
      mx = fmaxf(mx, __shfl_xor(mx, 8));
      float nm = fmaxf(m_run[r], mx);
      alpha[r] = __expf(m_run[r] - nm);
      m_run[r] = nm;
      pL[r] = __expf(sL - nm);
      pR[r] = __expf(sR - nm);
      float ps = pL[r] + pR[r];
      ps += __shfl_xor(ps, 1);
      ps += __shfl_xor(ps, 2);
      ps += __shfl_xor(ps, 4);
      ps += __shfl_xor(ps, 8);
      l_run[r] = l_run[r] * alpha[r] + ps;
    }
#pragma unroll
    for (int t = 0; t < 8; ++t)
#pragma unroll
      for (int r = 0; r < 4; ++r) acc[t][r] *= alpha[r];
    short* pw = &p_sh[wid * 16 * FPL];
#pragma unroll
    for (int r = 0; r < 4; ++r) {
      pw[(quad * 4 + r) * FPL + col] = cvt_bf16(pL[r]);
      pw[(quad * 4 + r) * FPL + col + 16] = cvt_bf16(pR[r]);
    }
    __syncthreads();
    short8 pa = *(const short8*)&pw[col * FPL + quad * 8];
#pragma unroll
    for (int t = 0; t < 8; ++t) {
      short8 vb = *(const short8*)&v_sh[(t * 16 + col) * FVL + quad * 8];
      acc[t] = __builtin_amdgcn_mfma_f32_16x16x32_bf16(asbf(pa), asbf(vb), acc[t], 0, 0, 0);
    }
  }
  float inv[4];
#pragma unroll
  for (int r = 0; r < 4; ++r) inv[r] = 1.f / l_run[r];
  float* ob = O + (size_t)(b * SEQ + q_reg_row) * QSTRIDE + h * HD;
#pragma unroll
  for (int r = 0; r < 4; ++r)
#pragma unroll
    for (int t = 0; t < 8; ++t)
      ob[(size_t)r * QSTRIDE + t * 16 + col] = acc[t][r] * inv[r];
}

extern "C" void kernel_launch(void* const* d_in, const int* in_sizes, int n_in,
                              void* d_out, int out_size, void* d_ws, size_t ws_size,
                              hipStream_t stream) {
  const float* Q = (const float*)d_in[0];
  const float* K = (const float*)d_in[1];
  const float* V = (const float*)d_in[2];
  float* O = (float*)d_out;
  const size_t kv_elems = (size_t)NB * KVH * SEQ * HD;  // 4,194,304
  const size_t need = kv_elems * 2 * sizeof(short);     // 16 MiB
  if (ws_size >= need) {
    short* Kbf = (short*)d_ws;
    short* Vtb = Kbf + kv_elems;
    convert_kv<<<3072, 256, 0, stream>>>(K, V, Kbf, Vtb);
    gqa_attn<<<1024, 256, 0, stream>>>(Q, Kbf, Vtb, O);
  } else {
    gqa_attn_f32<<<2048, 256, 0, stream>>>(Q, K, V, O);
  }
}